// Round 6
// baseline (3803.954 us; speedup 1.0000x reference)
//
#include <hip/hip_runtime.h>

// ---------------------------------------------------------------------------
// Round-11: fused 48-layer biLSTM — MERGED dual-direction recurrence.
//
// Evidence: round6->7 delta (570us = 110cy/step = exactly the step's VALU
// issue time) shows each rec wave's 447cy/step = ~110 issue + ~337 stall
// (chain latency + hazards), and the stall is dead time on a SIMD hosting
// only that wave. Fix: run BOTH direction chains in ONE wave, interleaved
// per iteration {F-step t, B-step 255-t}. The two independent ~160cy chains
// fill each other's stalls -> pair cost ~ max(2*issue, chain) ~= 220-340cy
// instead of 447/step.
//
//  - wave 0 (SIMD 0, alone; wave 4 barrier-idles there) runs both chains.
//  - Phase-A overlap on 6 waves {1,2,3,5,6,7} = 2 waves per SIMD 1..3:
//      S1 (pairs 192..223): gate rows 64..191   (ready after pair 191)
//      S2 (pairs 224..255): rows 32..63 & 192..223 (ready after 223)
//      tail: rows 0..31 & 224..255 (forced by dependency).
//  - Rec-wave registers kept lean: no whh double-buffer (one ~200cy L2
//    stall per layer), hs arrays land in SGPRs via readlane.
//  - Prefetch 1 row ahead per direction, unguarded (the final pair's OOB
//    prefetch stays inside the 128KB LDS block; value unused).
//  - Numerics identical to round-7/9/10 (absmax ~6e-5).
// ---------------------------------------------------------------------------

template <int SEL>
__device__ __forceinline__ float quad_bcast(float v) {
  return __int_as_float(__builtin_amdgcn_update_dpp(
      0, __float_as_int(v), SEL * 0x55, 0xF, 0xF, true));
}

__global__ __launch_bounds__(512, 1) void lstm_fused(
    const float* __restrict__ x, const float* __restrict__ W_ih0_1,
    const float* __restrict__ W_ih_1, const float* __restrict__ W_hh_1,
    const float* __restrict__ b_ih_1, const float* __restrict__ b_hh_1,
    const float* __restrict__ W_ih_2, const float* __restrict__ W_hh_2,
    const float* __restrict__ b_ih_2, const float* __restrict__ b_hh_2,
    float* __restrict__ x1out, float* __restrict__ h2out) {
  __shared__ float xgF[256 * 64];  // 64 KB, fwd direction
  __shared__ float xgB[256 * 64];  // 64 KB, bwd direction

  const int tid = threadIdx.x;
  const int lane = tid & 63;
  const int w = tid >> 6;     // 0..7
  const int np = blockIdx.x;  // 0..47
  const int nglob = 48 + np;  // stack-1 chain index

  const bool rec = (w == 0);

  // ---- layer-0 init (in_sz = 1) ----
  {
    const int dd = w >> 2;
    const int wv = w & 3;
    float* xg = dd ? xgB : xgF;
    const float bias = b_ih_1[dd * 64 + lane] + b_hh_1[dd * 64 + lane];
    const float wih0 = W_ih0_1[dd * 64 + lane];
    const int xvb = __float_as_int(x[(size_t)(wv * 64 + lane) * 96 + nglob]);
    for (int ti = 0; ti < 64; ++ti) {
      const float xs = __int_as_float(__builtin_amdgcn_readlane(xvb, ti));
      xg[(wv * 64 + ti) * 64 + lane] = fmaf(wih0, xs, bias);
    }
  }

  // ---- rec-wave persistent constants ----
  int g = 0, r = 0;
  float s_ = 0.f, m_ = 0.f, b_ = 0.f;
  if (rec) {
    g = lane & 3;
    r = g * 16 + (lane >> 2);
    s_ = (g == 2) ? 2.885390082f : -1.442695041f;
    m_ = (g == 2) ? -2.0f : 1.0f;
    b_ = (g == 2) ? 1.0f : 0.0f;
  }
  __syncthreads();

  for (int L = 0; L < 48; ++L) {
    const bool wo = (L == 23) || (L == 47);

    // ---- rec: load both directions' whh (raw loads; first gemv waits) ----
    float whF[16], whB[16];
    if (rec) {
      const float* Wl = ((L < 24) ? (W_hh_1 + (size_t)L * 2048)
                                  : (W_hh_2 + (size_t)(L - 24) * 2048)) +
                        (size_t)r * 16;
#pragma unroll
      for (int k = 0; k < 16; ++k) whF[k] = Wl[k];
#pragma unroll
      for (int k = 0; k < 16; ++k) whB[k] = Wl[1024 + k];
    }

    // ---- non-rec: prefetch phase-A weights for layer L+1 ----
    float wf[32], wb[32], bf = 0.f, bb = 0.f;
    if (!rec) {
      const int M = (L < 47) ? (L + 1) : 47;
      const float* WihP;
      const float* bihP;
      const float* bhhP;
      if (M < 24) {
        WihP = W_ih_1 + (size_t)(M - 1) * 4096;
        bihP = b_ih_1 + (size_t)M * 128;
        bhhP = b_hh_1 + (size_t)M * 128;
      } else {
        WihP = W_ih_2 + (size_t)(M - 24) * 4096;
        bihP = b_ih_2 + (size_t)(M - 24) * 128;
        bhhP = b_hh_2 + (size_t)(M - 24) * 128;
      }
      bf = bihP[lane] + bhhP[lane];
      bb = bihP[64 + lane] + bhhP[64 + lane];
      const float4* pf =
          reinterpret_cast<const float4*>(WihP + (size_t)lane * 32);
      const float4* pb =
          reinterpret_cast<const float4*>(WihP + 2048 + (size_t)lane * 32);
#pragma unroll
      for (int q = 0; q < 8; ++q) {
        const float4 a = pf[q];
        wf[4 * q + 0] = a.x;
        wf[4 * q + 1] = a.y;
        wf[4 * q + 2] = a.z;
        wf[4 * q + 3] = a.w;
        const float4 b = pb[q];
        wb[4 * q + 0] = b.x;
        wb[4 * q + 1] = b.y;
        wb[4 * q + 2] = b.z;
        wb[4 * q + 3] = b.w;
      }
    }

    // ---- phase-A helpers (non-rec waves only) ----
    auto compute_row = [&](int t, const float4 (&F)[4], const float4 (&Bv)[4]) {
      float f0 = bf, f1 = 0.f, f2 = 0.f, f3 = 0.f;
      float g0 = bb, g1 = 0.f, g2 = 0.f, g3 = 0.f;
#pragma unroll
      for (int q = 0; q < 4; ++q) {
        const float4 a = F[q];
        f0 = fmaf(wf[4 * q + 0], a.x, f0);
        f1 = fmaf(wf[4 * q + 1], a.y, f1);
        f2 = fmaf(wf[4 * q + 2], a.z, f2);
        f3 = fmaf(wf[4 * q + 3], a.w, f3);
        g0 = fmaf(wb[4 * q + 0], a.x, g0);
        g1 = fmaf(wb[4 * q + 1], a.y, g1);
        g2 = fmaf(wb[4 * q + 2], a.z, g2);
        g3 = fmaf(wb[4 * q + 3], a.w, g3);
        const float4 b = Bv[q];
        f0 = fmaf(wf[16 + 4 * q + 0], b.x, f0);
        f1 = fmaf(wf[16 + 4 * q + 1], b.y, f1);
        f2 = fmaf(wf[16 + 4 * q + 2], b.z, f2);
        f3 = fmaf(wf[16 + 4 * q + 3], b.w, f3);
        g0 = fmaf(wb[16 + 4 * q + 0], b.x, g0);
        g1 = fmaf(wb[16 + 4 * q + 1], b.y, g1);
        g2 = fmaf(wb[16 + 4 * q + 2], b.z, g2);
        g3 = fmaf(wb[16 + 4 * q + 3], b.w, g3);
      }
      xgF[t * 64 + lane] = (f0 + f1) + (f2 + f3);
      xgB[t * 64 + lane] = (g0 + g1) + (g2 + g3);
    };

    auto phaseA_rows = [&](int t0, int cnt) {  // cnt even, 2-row pipeline
      float4 af[4], ab4[4], nf[4], nb[4];
      {
        const float4* qf = reinterpret_cast<const float4*>(&xgF[t0 * 64]);
        const float4* qb = reinterpret_cast<const float4*>(&xgB[t0 * 64]);
#pragma unroll
        for (int q = 0; q < 4; ++q) {
          af[q] = qf[q];
          ab4[q] = qb[q];
        }
      }
      for (int i = 0; i < cnt; i += 2) {
        const int t = t0 + i;
        {
          const float4* qf =
              reinterpret_cast<const float4*>(&xgF[(t + 1) * 64]);
          const float4* qb =
              reinterpret_cast<const float4*>(&xgB[(t + 1) * 64]);
#pragma unroll
          for (int q = 0; q < 4; ++q) {
            nf[q] = qf[q];
            nb[q] = qb[q];
          }
        }
        compute_row(t, af, ab4);
        if (i + 2 < cnt) {
          const float4* qf =
              reinterpret_cast<const float4*>(&xgF[(t + 2) * 64]);
          const float4* qb =
              reinterpret_cast<const float4*>(&xgB[(t + 2) * 64]);
#pragma unroll
          for (int q = 0; q < 4; ++q) {
            af[q] = qf[q];
            ab4[q] = qb[q];
          }
        }
        compute_row(t + 1, nf, nb);
      }
    };

    // ---- merged phase-B state (rec wave) ----
    float hsF[16], hsB[16];
    float cF = 0.f, cB = 0.f;
    float curF = 0.f, curB = 0.f;
    float* apF = nullptr;
    float* apB = nullptr;

    // One iteration = {F-step t, B-step 255-t}; the two chains are
    // independent and interleave into each other's stall slots.
#define PAIR_STEP                                                         \
  {                                                                       \
    const float nxF = apF[64];  /* gate row t+1 (OOB at end: unused) */   \
    const float nxB = apB[-64]; /* gate row 254-t */                      \
    float fa0 = curF, fa1 = 0.f, fa2 = 0.f, fa3 = 0.f;                    \
    float ba0 = curB, ba1 = 0.f, ba2 = 0.f, ba3 = 0.f;                    \
    _Pragma("unroll") for (int k = 0; k < 16; k += 4) {                   \
      fa0 = fmaf(whF[k + 0], hsF[k + 0], fa0);                            \
      ba0 = fmaf(whB[k + 0], hsB[k + 0], ba0);                            \
      fa1 = fmaf(whF[k + 1], hsF[k + 1], fa1);                            \
      ba1 = fmaf(whB[k + 1], hsB[k + 1], ba1);                            \
      fa2 = fmaf(whF[k + 2], hsF[k + 2], fa2);                            \
      ba2 = fmaf(whB[k + 2], hsB[k + 2], ba2);                            \
      fa3 = fmaf(whF[k + 3], hsF[k + 3], fa3);                            \
      ba3 = fmaf(whB[k + 3], hsB[k + 3], ba3);                            \
    }                                                                     \
    const float gvF = (fa0 + fa1) + (fa2 + fa3);                          \
    const float gvB = (ba0 + ba1) + (ba2 + ba3);                          \
    const float eF = __builtin_amdgcn_exp2f(s_ * gvF);                    \
    const float eB = __builtin_amdgcn_exp2f(s_ * gvB);                    \
    const float vF = fmaf(m_, __builtin_amdgcn_rcpf(1.0f + eF), b_);      \
    const float vB = fmaf(m_, __builtin_amdgcn_rcpf(1.0f + eB), b_);      \
    const float siF = quad_bcast<0>(vF);                                  \
    const float siB = quad_bcast<0>(vB);                                  \
    const float sfF = quad_bcast<1>(vF);                                  \
    const float sfB = quad_bcast<1>(vB);                                  \
    const float tgF = quad_bcast<2>(vF);                                  \
    const float tgB = quad_bcast<2>(vB);                                  \
    const float soF = quad_bcast<3>(vF);                                  \
    const float soB = quad_bcast<3>(vB);                                  \
    cF = fmaf(sfF, cF, siF * tgF);                                        \
    cB = fmaf(sfB, cB, siB * tgB);                                        \
    const float e2F = __builtin_amdgcn_exp2f(2.885390082f * cF);          \
    const float e2B = __builtin_amdgcn_exp2f(2.885390082f * cB);          \
    const float thF = fmaf(-2.0f, __builtin_amdgcn_rcpf(1.0f + e2F), 1.0f); \
    const float thB = fmaf(-2.0f, __builtin_amdgcn_rcpf(1.0f + e2B), 1.0f); \
    const float hF = soF * thF;                                           \
    const float hB = soB * thB;                                           \
    apF[0] = hF; /* g==0 lanes land h[j] compactly at [0..15] */          \
    apB[0] = hB;                                                          \
    const int hbF = __float_as_int(hF);                                   \
    const int hbB = __float_as_int(hB);                                   \
    _Pragma("unroll") for (int k = 0; k < 16; ++k) {                      \
      hsF[k] = __int_as_float(__builtin_amdgcn_readlane(hbF, 4 * k));     \
      hsB[k] = __int_as_float(__builtin_amdgcn_readlane(hbB, 4 * k));     \
    }                                                                     \
    curF = nxF;                                                           \
    curB = nxB;                                                           \
    apF += 64;                                                            \
    apB -= 64;                                                            \
  }

    // ---- S0: pairs 0..191 ----
    if (rec) {
#pragma unroll
      for (int k = 0; k < 16; ++k) {
        hsF[k] = 0.f;
        hsB[k] = 0.f;
      }
      cF = 0.f;
      cB = 0.f;
      apF = &xgF[r];
      apB = &xgB[255 * 64 + r];
      curF = apF[0];
      curB = apB[0];
      for (int it = 0; it < 192; ++it) PAIR_STEP
    }
    __syncthreads();  // B_a

    // ---- S1: pairs 192..223 || phase-A rows 64..191 (6 waves) ----
    if (rec) {
      for (int it = 0; it < 32; ++it) PAIR_STEP
    } else if (w != 4 && !wo) {
      const int widx6 = (w < 4) ? (w - 1) : (w - 2);  // 0..5
      const int t0 =
          64 + ((widx6 < 4) ? 22 * widx6 : 88 + 20 * (widx6 - 4));
      phaseA_rows(t0, (widx6 < 4) ? 22 : 20);
    }
    __syncthreads();  // B_b

    // ---- S2: pairs 224..255 || phase-A rows 32..63 & 192..223 ----
    if (rec) {
      for (int it = 0; it < 32; ++it) PAIR_STEP
    } else if (w != 4 && !wo) {
      const int k3 = (w < 4) ? (w - 1) : (w - 5);  // 0..2
      const int base = (w < 4) ? 32 : 192;
      phaseA_rows(base + ((k3 == 0) ? 0 : (12 + 10 * (k3 - 1))),
                  (k3 == 0) ? 12 : 10);
    }
#undef PAIR_STEP
    __syncthreads();  // B_c

    // ---- write-outs / tail phase-A ----
    if (wo) {
      float* dst = (L == 23) ? x1out : h2out;
#pragma unroll
      for (int p = 0; p < 4; ++p) {
        const int gi = p * 512 + tid;  // 0..2047 float4 chunks
        const int tt = gi >> 3;
        const int cc = gi & 7;  // 0-3 fwd, 4-7 bwd
        const float* src =
            (cc < 4) ? &xgF[tt * 64 + cc * 4] : &xgB[tt * 64 + (cc - 4) * 4];
        const float4 v = *reinterpret_cast<const float4*>(src);
        *reinterpret_cast<float4*>(dst + ((size_t)tt * 48 + np) * 32 +
                                   cc * 4) = v;
      }
      if (L == 47) break;
      __syncthreads();  // protect x1 reads from phase-A overwrite
      if (!rec) {       // full phase A: waves 1..7, all 256 rows
        int t0, cnt;
        if (w <= 4) {
          t0 = 38 * (w - 1);
          cnt = 38;
        } else if (w == 5) {
          t0 = 152;
          cnt = 36;
        } else {
          t0 = 188 + 34 * (w - 6);
          cnt = 34;
        }
        phaseA_rows(t0, cnt);
      }
    } else {
      if (!rec && w != 4) {  // tail rows 0..31 & 224..255 (6 waves)
        const int k3 = (w < 4) ? (w - 1) : (w - 5);  // 0..2
        const int base = (w < 4) ? 0 : 224;
        phaseA_rows(base + ((k3 == 0) ? 0 : (12 + 10 * (k3 - 1))),
                    (k3 == 0) ? 12 : 10);
      }
    }
    __syncthreads();  // B_d
  }
}

// fc1: y1[b,m] = relu( sum_k (h2[b,k] + x1[b,k]) * w1[m,k] + b1[m] )
// Both h2 and x1 are compact (256,1536).
__global__ __launch_bounds__(256) void fc1_kernel(
    const float* __restrict__ h2, const float* __restrict__ x1b,
    const float* __restrict__ w1, const float* __restrict__ b1,
    float* __restrict__ y1) {
  __shared__ float Zs[16][68];
  __shared__ float Ws[16][68];
  const int tid = threadIdx.x;
  const int m0 = blockIdx.x * 64;
  const int b0 = blockIdx.y * 64;
  const int rr = tid >> 2;
  const int c4 = (tid & 3) * 4;
  const int tx = tid & 15, ty = tid >> 4;

  float acc[4][4];
#pragma unroll
  for (int i = 0; i < 4; ++i)
#pragma unroll
    for (int jj = 0; jj < 4; ++jj) acc[i][jj] = 0.f;

  const bool wvalid = (m0 + rr) < 1000;
  const float* zr = h2 + (size_t)(b0 + rr) * 1536 + c4;
  const float* zr2 = x1b + (size_t)(b0 + rr) * 1536 + c4;
  const float* wr = w1 + (size_t)(m0 + rr) * 1536 + c4;

  float4 za = *reinterpret_cast<const float4*>(zr);
  float4 zb = *reinterpret_cast<const float4*>(zr2);
  float4 wv = wvalid ? *reinterpret_cast<const float4*>(wr)
                     : make_float4(0.f, 0.f, 0.f, 0.f);

  for (int k0 = 0; k0 < 1536; k0 += 16) {
    Zs[c4 + 0][rr] = za.x + zb.x;
    Zs[c4 + 1][rr] = za.y + zb.y;
    Zs[c4 + 2][rr] = za.z + zb.z;
    Zs[c4 + 3][rr] = za.w + zb.w;
    Ws[c4 + 0][rr] = wv.x;
    Ws[c4 + 1][rr] = wv.y;
    Ws[c4 + 2][rr] = wv.z;
    Ws[c4 + 3][rr] = wv.w;
    if (k0 + 16 < 1536) {
      za = *reinterpret_cast<const float4*>(zr + k0 + 16);
      zb = *reinterpret_cast<const float4*>(zr2 + k0 + 16);
      if (wvalid) wv = *reinterpret_cast<const float4*>(wr + k0 + 16);
    }
    __syncthreads();
#pragma unroll
    for (int kk = 0; kk < 16; ++kk) {
      const float4 av = *reinterpret_cast<const float4*>(&Zs[kk][ty * 4]);
      const float4 bv = *reinterpret_cast<const float4*>(&Ws[kk][tx * 4]);
      const float a_[4] = {av.x, av.y, av.z, av.w};
      const float b_[4] = {bv.x, bv.y, bv.z, bv.w};
#pragma unroll
      for (int i = 0; i < 4; ++i)
#pragma unroll
        for (int jj = 0; jj < 4; ++jj)
          acc[i][jj] = fmaf(a_[i], b_[jj], acc[i][jj]);
    }
    __syncthreads();
  }
#pragma unroll
  for (int i = 0; i < 4; ++i) {
    const int b = b0 + ty * 4 + i;
#pragma unroll
    for (int jj = 0; jj < 4; ++jj) {
      const int m = m0 + tx * 4 + jj;
      if (m < 1000) {
        float vo = acc[i][jj] + b1[m];
        y1[(size_t)b * 1000 + m] = vo > 0.f ? vo : 0.f;
      }
    }
  }
}

// fc2: out[b,p] = sum_m y1[b,m]*w2[p,m] + b2[p], p<48; FP32 store.
__global__ __launch_bounds__(64) void fc2_kernel(
    const float* __restrict__ y1, const float* __restrict__ w2,
    const float* __restrict__ b2, float* __restrict__ out) {
  __shared__ float ys[1000];
  const int b = blockIdx.x;
  for (int k = threadIdx.x; k < 1000; k += 64) ys[k] = y1[(size_t)b * 1000 + k];
  __syncthreads();
  const int p = threadIdx.x;
  if (p < 48) {
    float a0 = b2[p], a1 = 0.f, a2 = 0.f, a3 = 0.f;
    const float* wr = w2 + (size_t)p * 1000;
    for (int k = 0; k < 1000; k += 4) {
      const float4 wv = *reinterpret_cast<const float4*>(wr + k);
      a0 = fmaf(ys[k + 0], wv.x, a0);
      a1 = fmaf(ys[k + 1], wv.y, a1);
      a2 = fmaf(ys[k + 2], wv.z, a2);
      a3 = fmaf(ys[k + 3], wv.w, a3);
    }
    out[(size_t)b * 48 + p] = (a0 + a1) + (a2 + a3);
  }
}

extern "C" void kernel_launch(void* const* d_in, const int* in_sizes, int n_in,
                              void* d_out, int out_size, void* d_ws,
                              size_t ws_size, hipStream_t stream) {
  const float* x = (const float*)d_in[0];
  const float* W_ih0_1 = (const float*)d_in[1];
  const float* W_ih_1 = (const float*)d_in[2];
  const float* W_hh_1 = (const float*)d_in[3];
  const float* b_ih_1 = (const float*)d_in[4];
  const float* b_hh_1 = (const float*)d_in[5];
  const float* W_ih_2 = (const float*)d_in[6];
  const float* W_hh_2 = (const float*)d_in[7];
  const float* b_ih_2 = (const float*)d_in[8];
  const float* b_hh_2 = (const float*)d_in[9];
  const float* fc1_w = (const float*)d_in[10];
  const float* fc1_b = (const float*)d_in[11];
  const float* fc2_w = (const float*)d_in[12];
  const float* fc2_b = (const float*)d_in[13];

  float* ws = (float*)d_ws;
  float* x1b = ws;           // 393216 floats (256*48*32)
  float* h2b = ws + 393216;  // 393216 floats
  float* y1 = ws + 786432;   // 256000 floats

  lstm_fused<<<48, 512, 0, stream>>>(x, W_ih0_1, W_ih_1, W_hh_1, b_ih_1,
                                     b_hh_1, W_ih_2, W_hh_2, b_ih_2, b_hh_2,
                                     x1b, h2b);
  fc1_kernel<<<dim3(16, 4), 256, 0, stream>>>(h2b, x1b, fc1_w, fc1_b, y1);
  fc2_kernel<<<256, 64, 0, stream>>>(y1, fc2_w, fc2_b, (float*)d_out);
}

// Round 7
// 3434.224 us; speedup vs baseline: 1.1077x; 1.1077x over previous
//
#include <hip/hip_runtime.h>

// ---------------------------------------------------------------------------
// Round-12: fused 48-layer biLSTM — merged dual-direction recurrence in a
// 256-thread / 4-wave block (1 wave per SIMD -> no issue sharing, and the
// register regime where previous kernels provably did not spill).
//
// Evidence backbone:
//  - Phase B is ~100% of runtime (47us/layer = 256 steps x ~450cy).
//  - Round-6->7: removing SIMD sharing between the two rec waves saved
//    110cy/step => stall cycles are fillable by independent work.
//  - Round-11 (merge in 512-thread kernel) spilled (WRITE_SIZE 41MB,
//    VGPR pinned at 128 for 512-thread blocks) and regressed.
//
// Structure:
//  - Wave 0: BOTH direction chains, interleaved per iteration
//    {F-step t, B-step 255-t}. Two independent ~160cy chains fill each
//    other's stall/hazard slots. Alone on SIMD 0.
//  - Waves 1-3 (SIMDs 1-3): all of phase A (gates of layer L+1).
//      S1 (pairs 192..255): rows 64..191 (ready after pair 191).
//      tail: rows 0..63 & 192..255 (ready only after phase B ends).
//  - Rec wave never loads phase-A weights (lean live set).
//  - LDS 128KB: xgF/xgB [256][64]; phase B overwrites consumed gate rows
//    with h (g==0 lanes land h[j] compactly at positions [0..15]).
//  - Only x1 (L=23) and h2 (L=47) go to global, compact (t*48+n)*32.
//  - Numerics identical to rounds 7/9/10 (absmax ~6e-5).
// ---------------------------------------------------------------------------

template <int SEL>
__device__ __forceinline__ float quad_bcast(float v) {
  return __int_as_float(__builtin_amdgcn_update_dpp(
      0, __float_as_int(v), SEL * 0x55, 0xF, 0xF, true));
}

__global__ __launch_bounds__(256) void lstm_fused(
    const float* __restrict__ x, const float* __restrict__ W_ih0_1,
    const float* __restrict__ W_ih_1, const float* __restrict__ W_hh_1,
    const float* __restrict__ b_ih_1, const float* __restrict__ b_hh_1,
    const float* __restrict__ W_ih_2, const float* __restrict__ W_hh_2,
    const float* __restrict__ b_ih_2, const float* __restrict__ b_hh_2,
    float* __restrict__ x1out, float* __restrict__ h2out) {
  __shared__ float xgF[256 * 64];  // 64 KB, fwd
  __shared__ float xgB[256 * 64];  // 64 KB, bwd

  const int tid = threadIdx.x;
  const int lane = tid & 63;
  const int w = tid >> 6;     // 0..3, one wave per SIMD
  const int np = blockIdx.x;  // 0..47
  const int nglob = 48 + np;  // stack-1 chain index (n<48 dead)

  const bool rec = (w == 0);

  // ---- layer-0 init (in_sz = 1): wave w covers t in [w*64, w*64+64) ----
  {
    const float bF = b_ih_1[lane] + b_hh_1[lane];
    const float bB = b_ih_1[64 + lane] + b_hh_1[64 + lane];
    const float wF = W_ih0_1[lane];
    const float wB = W_ih0_1[64 + lane];
    const int xvb = __float_as_int(x[(size_t)(w * 64 + lane) * 96 + nglob]);
    for (int ti = 0; ti < 64; ++ti) {
      const float xs = __int_as_float(__builtin_amdgcn_readlane(xvb, ti));
      xgF[(w * 64 + ti) * 64 + lane] = fmaf(wF, xs, bF);
      xgB[(w * 64 + ti) * 64 + lane] = fmaf(wB, xs, bB);
    }
  }

  // ---- rec-wave persistent constants ----
  const int g = lane & 3;
  const int r = (g) * 16 + (lane >> 2);
  const float s_ = (g == 2) ? 2.885390082f : -1.442695041f;
  const float m_ = (g == 2) ? -2.0f : 1.0f;
  const float b_ = (g == 2) ? 1.0f : 0.0f;
  __syncthreads();

  for (int L = 0; L < 48; ++L) {
    const bool wo = (L == 23) || (L == 47);

    // ---- rec: load both directions' whh (raw loads; first gemv waits) ----
    float whF[16], whB[16];
    if (rec) {
      const float* Wl = ((L < 24) ? (W_hh_1 + (size_t)L * 2048)
                                  : (W_hh_2 + (size_t)(L - 24) * 2048)) +
                        (size_t)r * 16;
#pragma unroll
      for (int k = 0; k < 16; ++k) whF[k] = Wl[k];
#pragma unroll
      for (int k = 0; k < 16; ++k) whB[k] = Wl[1024 + k];
    }

    // ---- waves 1-3: prefetch phase-A weights for layer L+1 ----
    float wf[32], wb[32], bf = 0.f, bb = 0.f;
    if (!rec) {
      const int M = (L < 47) ? (L + 1) : 47;  // clamp (last unused)
      const float* WihP;
      const float* bihP;
      const float* bhhP;
      if (M < 24) {
        WihP = W_ih_1 + (size_t)(M - 1) * 4096;
        bihP = b_ih_1 + (size_t)M * 128;
        bhhP = b_hh_1 + (size_t)M * 128;
      } else {
        WihP = W_ih_2 + (size_t)(M - 24) * 4096;
        bihP = b_ih_2 + (size_t)(M - 24) * 128;
        bhhP = b_hh_2 + (size_t)(M - 24) * 128;
      }
      bf = bihP[lane] + bhhP[lane];
      bb = bihP[64 + lane] + bhhP[64 + lane];
      const float4* pf =
          reinterpret_cast<const float4*>(WihP + (size_t)lane * 32);
      const float4* pb =
          reinterpret_cast<const float4*>(WihP + 2048 + (size_t)lane * 32);
#pragma unroll
      for (int q = 0; q < 8; ++q) {
        const float4 a = pf[q];
        wf[4 * q + 0] = a.x;
        wf[4 * q + 1] = a.y;
        wf[4 * q + 2] = a.z;
        wf[4 * q + 3] = a.w;
        const float4 b = pb[q];
        wb[4 * q + 0] = b.x;
        wb[4 * q + 1] = b.y;
        wb[4 * q + 2] = b.z;
        wb[4 * q + 3] = b.w;
      }
    }

    // ---- phase-A helpers (waves 1-3 only) ----
    auto compute_row = [&](int t, const float4 (&F)[4], const float4 (&Bv)[4]) {
      float f0 = bf, f1 = 0.f, f2 = 0.f, f3 = 0.f;
      float g0 = bb, g1 = 0.f, g2 = 0.f, g3 = 0.f;
#pragma unroll
      for (int q = 0; q < 4; ++q) {
        const float4 a = F[q];
        f0 = fmaf(wf[4 * q + 0], a.x, f0);
        f1 = fmaf(wf[4 * q + 1], a.y, f1);
        f2 = fmaf(wf[4 * q + 2], a.z, f2);
        f3 = fmaf(wf[4 * q + 3], a.w, f3);
        g0 = fmaf(wb[4 * q + 0], a.x, g0);
        g1 = fmaf(wb[4 * q + 1], a.y, g1);
        g2 = fmaf(wb[4 * q + 2], a.z, g2);
        g3 = fmaf(wb[4 * q + 3], a.w, g3);
        const float4 b = Bv[q];
        f0 = fmaf(wf[16 + 4 * q + 0], b.x, f0);
        f1 = fmaf(wf[16 + 4 * q + 1], b.y, f1);
        f2 = fmaf(wf[16 + 4 * q + 2], b.z, f2);
        f3 = fmaf(wf[16 + 4 * q + 3], b.w, f3);
        g0 = fmaf(wb[16 + 4 * q + 0], b.x, g0);
        g1 = fmaf(wb[16 + 4 * q + 1], b.y, g1);
        g2 = fmaf(wb[16 + 4 * q + 2], b.z, g2);
        g3 = fmaf(wb[16 + 4 * q + 3], b.w, g3);
      }
      xgF[t * 64 + lane] = (f0 + f1) + (f2 + f3);
      xgB[t * 64 + lane] = (g0 + g1) + (g2 + g3);
    };

    auto phaseA_rows = [&](int t0, int cnt) {  // cnt even, 2-row pipeline
      float4 af[4], ab4[4], nf[4], nb[4];
      {
        const float4* qf = reinterpret_cast<const float4*>(&xgF[t0 * 64]);
        const float4* qb = reinterpret_cast<const float4*>(&xgB[t0 * 64]);
#pragma unroll
        for (int q = 0; q < 4; ++q) {
          af[q] = qf[q];
          ab4[q] = qb[q];
        }
      }
      for (int i = 0; i < cnt; i += 2) {
        const int t = t0 + i;
        {
          const float4* qf =
              reinterpret_cast<const float4*>(&xgF[(t + 1) * 64]);
          const float4* qb =
              reinterpret_cast<const float4*>(&xgB[(t + 1) * 64]);
#pragma unroll
          for (int q = 0; q < 4; ++q) {
            nf[q] = qf[q];
            nb[q] = qb[q];
          }
        }
        compute_row(t, af, ab4);
        if (i + 2 < cnt) {
          const float4* qf =
              reinterpret_cast<const float4*>(&xgF[(t + 2) * 64]);
          const float4* qb =
              reinterpret_cast<const float4*>(&xgB[(t + 2) * 64]);
#pragma unroll
          for (int q = 0; q < 4; ++q) {
            af[q] = qf[q];
            ab4[q] = qb[q];
          }
        }
        compute_row(t + 1, nf, nb);
      }
    };

    // ---- merged phase-B state (wave 0) ----
    float hsF[16], hsB[16];
    float cF = 0.f, cB = 0.f;
    float curF = 0.f, curB = 0.f;
    float* apF = nullptr;
    float* apB = nullptr;

    // One iteration = {F-step t, B-step 255-t}; independent chains
    // interleave into each other's stall/hazard slots.
#define PAIR_STEP                                                           \
  {                                                                         \
    const float nxF = apF[64];  /* gate row t+1 (final: harmless OOB-in-LDS \
                                   read into xgB; value unused) */          \
    const float nxB = apB[-64]; /* gate row 254-t (final: reads xgF end) */ \
    float fa0 = curF, fa1 = 0.f, fa2 = 0.f, fa3 = 0.f;                      \
    float ba0 = curB, ba1 = 0.f, ba2 = 0.f, ba3 = 0.f;                      \
    _Pragma("unroll") for (int k = 0; k < 16; k += 4) {                     \
      fa0 = fmaf(whF[k + 0], hsF[k + 0], fa0);                              \
      ba0 = fmaf(whB[k + 0], hsB[k + 0], ba0);                              \
      fa1 = fmaf(whF[k + 1], hsF[k + 1], fa1);                              \
      ba1 = fmaf(whB[k + 1], hsB[k + 1], ba1);                              \
      fa2 = fmaf(whF[k + 2], hsF[k + 2], fa2);                              \
      ba2 = fmaf(whB[k + 2], hsB[k + 2], ba2);                              \
      fa3 = fmaf(whF[k + 3], hsF[k + 3], fa3);                              \
      ba3 = fmaf(whB[k + 3], hsB[k + 3], ba3);                              \
    }                                                                       \
    const float gvF = (fa0 + fa1) + (fa2 + fa3);                            \
    const float gvB = (ba0 + ba1) + (ba2 + ba3);                            \
    const float eF = __builtin_amdgcn_exp2f(s_ * gvF);                      \
    const float eB = __builtin_amdgcn_exp2f(s_ * gvB);                      \
    const float vF = fmaf(m_, __builtin_amdgcn_rcpf(1.0f + eF), b_);        \
    const float vB = fmaf(m_, __builtin_amdgcn_rcpf(1.0f + eB), b_);        \
    const float siF = quad_bcast<0>(vF);                                    \
    const float siB = quad_bcast<0>(vB);                                    \
    const float sfF = quad_bcast<1>(vF);                                    \
    const float sfB = quad_bcast<1>(vB);                                    \
    const float tgF = quad_bcast<2>(vF);                                    \
    const float tgB = quad_bcast<2>(vB);                                    \
    const float soF = quad_bcast<3>(vF);                                    \
    const float soB = quad_bcast<3>(vB);                                    \
    cF = fmaf(sfF, cF, siF * tgF);                                          \
    cB = fmaf(sfB, cB, siB * tgB);                                          \
    const float e2F = __builtin_amdgcn_exp2f(2.885390082f * cF);            \
    const float e2B = __builtin_amdgcn_exp2f(2.885390082f * cB);            \
    const float thF = fmaf(-2.0f, __builtin_amdgcn_rcpf(1.0f + e2F), 1.0f); \
    const float thB = fmaf(-2.0f, __builtin_amdgcn_rcpf(1.0f + e2B), 1.0f); \
    const float hF = soF * thF;                                             \
    const float hB = soB * thB;                                             \
    apF[0] = hF; /* g==0 lanes land h[j] compactly at [0..15] */            \
    apB[0] = hB;                                                            \
    const int hbF = __float_as_int(hF);                                     \
    const int hbB = __float_as_int(hB);                                     \
    _Pragma("unroll") for (int k = 0; k < 16; ++k) {                        \
      hsF[k] = __int_as_float(__builtin_amdgcn_readlane(hbF, 4 * k));       \
      hsB[k] = __int_as_float(__builtin_amdgcn_readlane(hbB, 4 * k));       \
    }                                                                       \
    curF = nxF;                                                             \
    curB = nxB;                                                             \
    apF += 64;                                                              \
    apB -= 64;                                                              \
  }

    // ---- S0: pairs 0..191 (waves 1-3 wait at B_a) ----
    if (rec) {
#pragma unroll
      for (int k = 0; k < 16; ++k) {
        hsF[k] = 0.f;
        hsB[k] = 0.f;
      }
      cF = 0.f;
      cB = 0.f;
      apF = &xgF[r];
      apB = &xgB[255 * 64 + r];
      curF = apF[0];
      curB = apB[0];
      for (int it = 0; it < 192; ++it) PAIR_STEP
    }
    __syncthreads();  // B_a

    // ---- S1: pairs 192..255 || phase-A rows 64..191 on waves 1-3 ----
    if (rec) {
      for (int it = 0; it < 64; ++it) PAIR_STEP
    } else if (!wo) {
      if (w == 1)
        phaseA_rows(64, 44);
      else if (w == 2)
        phaseA_rows(108, 44);
      else
        phaseA_rows(152, 40);
    }
#undef PAIR_STEP
    __syncthreads();  // B_b

    // ---- write-outs / remaining phase A ----
    if (wo) {
      float* dst = (L == 23) ? x1out : h2out;
#pragma unroll
      for (int p = 0; p < 8; ++p) {
        const int gi = p * 256 + tid;  // 0..2047 float4 chunks
        const int tt = gi >> 3;
        const int cc = gi & 7;  // 0-3 fwd, 4-7 bwd
        const float* src =
            (cc < 4) ? &xgF[tt * 64 + cc * 4] : &xgB[tt * 64 + (cc - 4) * 4];
        const float4 v = *reinterpret_cast<const float4*>(src);
        *reinterpret_cast<float4*>(dst + ((size_t)tt * 48 + np) * 32 +
                                   cc * 4) = v;
      }
      if (L == 47) break;
      __syncthreads();  // protect x1 reads from phase-A overwrite
      // full phase A on waves 1-3: {86,86,84} rows
      if (w == 1)
        phaseA_rows(0, 86);
      else if (w == 2)
        phaseA_rows(86, 86);
      else if (w == 3)
        phaseA_rows(172, 84);
    } else {
      // tail rows 0..63 & 192..255 on waves 1-3: {44, 20+20, 44}
      if (w == 1) {
        phaseA_rows(0, 44);
      } else if (w == 2) {
        phaseA_rows(44, 20);
        phaseA_rows(192, 20);
      } else if (w == 3) {
        phaseA_rows(212, 44);
      }
    }
    __syncthreads();  // B_c
  }
}

// fc1: y1[b,m] = relu( sum_k (h2[b,k] + x1[b,k]) * w1[m,k] + b1[m] )
// Both h2 and x1 are compact (256,1536).
__global__ __launch_bounds__(256) void fc1_kernel(
    const float* __restrict__ h2, const float* __restrict__ x1b,
    const float* __restrict__ w1, const float* __restrict__ b1,
    float* __restrict__ y1) {
  __shared__ float Zs[16][68];
  __shared__ float Ws[16][68];
  const int tid = threadIdx.x;
  const int m0 = blockIdx.x * 64;
  const int b0 = blockIdx.y * 64;
  const int rr = tid >> 2;
  const int c4 = (tid & 3) * 4;
  const int tx = tid & 15, ty = tid >> 4;

  float acc[4][4];
#pragma unroll
  for (int i = 0; i < 4; ++i)
#pragma unroll
    for (int jj = 0; jj < 4; ++jj) acc[i][jj] = 0.f;

  const bool wvalid = (m0 + rr) < 1000;
  const float* zr = h2 + (size_t)(b0 + rr) * 1536 + c4;
  const float* zr2 = x1b + (size_t)(b0 + rr) * 1536 + c4;
  const float* wr = w1 + (size_t)(m0 + rr) * 1536 + c4;

  float4 za = *reinterpret_cast<const float4*>(zr);
  float4 zb = *reinterpret_cast<const float4*>(zr2);
  float4 wv = wvalid ? *reinterpret_cast<const float4*>(wr)
                     : make_float4(0.f, 0.f, 0.f, 0.f);

  for (int k0 = 0; k0 < 1536; k0 += 16) {
    Zs[c4 + 0][rr] = za.x + zb.x;
    Zs[c4 + 1][rr] = za.y + zb.y;
    Zs[c4 + 2][rr] = za.z + zb.z;
    Zs[c4 + 3][rr] = za.w + zb.w;
    Ws[c4 + 0][rr] = wv.x;
    Ws[c4 + 1][rr] = wv.y;
    Ws[c4 + 2][rr] = wv.z;
    Ws[c4 + 3][rr] = wv.w;
    if (k0 + 16 < 1536) {
      za = *reinterpret_cast<const float4*>(zr + k0 + 16);
      zb = *reinterpret_cast<const float4*>(zr2 + k0 + 16);
      if (wvalid) wv = *reinterpret_cast<const float4*>(wr + k0 + 16);
    }
    __syncthreads();
#pragma unroll
    for (int kk = 0; kk < 16; ++kk) {
      const float4 av = *reinterpret_cast<const float4*>(&Zs[kk][ty * 4]);
      const float4 bv = *reinterpret_cast<const float4*>(&Ws[kk][tx * 4]);
      const float a_[4] = {av.x, av.y, av.z, av.w};
      const float b_[4] = {bv.x, bv.y, bv.z, bv.w};
#pragma unroll
      for (int i = 0; i < 4; ++i)
#pragma unroll
        for (int jj = 0; jj < 4; ++jj)
          acc[i][jj] = fmaf(a_[i], b_[jj], acc[i][jj]);
    }
    __syncthreads();
  }
#pragma unroll
  for (int i = 0; i < 4; ++i) {
    const int b = b0 + ty * 4 + i;
#pragma unroll
    for (int jj = 0; jj < 4; ++jj) {
      const int m = m0 + tx * 4 + jj;
      if (m < 1000) {
        float vo = acc[i][jj] + b1[m];
        y1[(size_t)b * 1000 + m] = vo > 0.f ? vo : 0.f;
      }
    }
  }
}

// fc2: out[b,p] = sum_m y1[b,m]*w2[p,m] + b2[p], p<48; FP32 store.
__global__ __launch_bounds__(64) void fc2_kernel(
    const float* __restrict__ y1, const float* __restrict__ w2,
    const float* __restrict__ b2, float* __restrict__ out) {
  __shared__ float ys[1000];
  const int b = blockIdx.x;
  for (int k = threadIdx.x; k < 1000; k += 64) ys[k] = y1[(size_t)b * 1000 + k];
  __syncthreads();
  const int p = threadIdx.x;
  if (p < 48) {
    float a0 = b2[p], a1 = 0.f, a2 = 0.f, a3 = 0.f;
    const float* wr = w2 + (size_t)p * 1000;
    for (int k = 0; k < 1000; k += 4) {
      const float4 wv = *reinterpret_cast<const float4*>(wr + k);
      a0 = fmaf(ys[k + 0], wv.x, a0);
      a1 = fmaf(ys[k + 1], wv.y, a1);
      a2 = fmaf(ys[k + 2], wv.z, a2);
      a3 = fmaf(ys[k + 3], wv.w, a3);
    }
    out[(size_t)b * 48 + p] = (a0 + a1) + (a2 + a3);
  }
}

extern "C" void kernel_launch(void* const* d_in, const int* in_sizes, int n_in,
                              void* d_out, int out_size, void* d_ws,
                              size_t ws_size, hipStream_t stream) {
  const float* x = (const float*)d_in[0];
  const float* W_ih0_1 = (const float*)d_in[1];
  const float* W_ih_1 = (const float*)d_in[2];
  const float* W_hh_1 = (const float*)d_in[3];
  const float* b_ih_1 = (const float*)d_in[4];
  const float* b_hh_1 = (const float*)d_in[5];
  const float* W_ih_2 = (const float*)d_in[6];
  const float* W_hh_2 = (const float*)d_in[7];
  const float* b_ih_2 = (const float*)d_in[8];
  const float* b_hh_2 = (const float*)d_in[9];
  const float* fc1_w = (const float*)d_in[10];
  const float* fc1_b = (const float*)d_in[11];
  const float* fc2_w = (const float*)d_in[12];
  const float* fc2_b = (const float*)d_in[13];

  float* ws = (float*)d_ws;
  float* x1b = ws;           // 393216 floats (256*48*32)
  float* h2b = ws + 393216;  // 393216 floats
  float* y1 = ws + 786432;   // 256000 floats

  lstm_fused<<<48, 256, 0, stream>>>(x, W_ih0_1, W_ih_1, W_hh_1, b_ih_1,
                                     b_hh_1, W_ih_2, W_hh_2, b_ih_2, b_hh_2,
                                     x1b, h2b);
  fc1_kernel<<<dim3(16, 4), 256, 0, stream>>>(h2b, x1b, fc1_w, fc1_b, y1);
  fc2_kernel<<<256, 64, 0, stream>>>(y1, fc2_w, fc2_b, (float*)d_out);
}

// Round 9
// 2421.446 us; speedup vs baseline: 1.5709x; 1.4183x over previous
//
#include <hip/hip_runtime.h>

// ---------------------------------------------------------------------------
// Round-14 (= round-13 resubmit, deduped): fused 48-layer biLSTM with
// LDS-free inner recurrence (register segment preload).
//
// Round-13 never ran (infra: "MI355X container failed twice"). Changes vs
// round-13: fwd/bwd recurrence merged into ONE stride-parameterized segment
// routine (wave 0: st=+64 from row 0; wave 1: st=-64 from row 255) to halve
// code size. Numerics and schedule identical.
//
// Hypothesis under test: the ~447cy/step invariant (rounds 5-12) is caused
// by per-step ds_read+ds_write forcing conservative lgkmcnt(0) drains in
// the serial loop. Segment = {32 batched ds_read_b32 of this lane's gate
// column, 32 fully-unrolled register-only steps, fire-and-forget h writes}.
//
// Structure: 256 threads / 4 waves (1 wave/SIMD; the 512-thread 128-VGPR
// cap caused rounds 8/9/11 spills):
//   wave 0 = fwd rec (SIMD 0), wave 1 = bwd rec (SIMD 1),
//   waves 2,3 = phase A (SIMDs 2,3):
//     S1 (rec steps 192..223): gate rows 64..191 of layer L+1
//     S2 (rec steps 224..255): rows 32..63 & 192..223
//     tail: rows 0..31 & 224..255; full 256 rows after write-out layers.
// Only x1 (L=23) and h2 (L=47) go to global, compact (t*48+n)*32 layout.
// Numerics identical to rounds 7/9/10/12 (absmax ~6e-5).
// ---------------------------------------------------------------------------

template <int SEL>
__device__ __forceinline__ float quad_bcast(float v) {
  return __int_as_float(__builtin_amdgcn_update_dpp(
      0, __float_as_int(v), SEL * 0x55, 0xF, 0xF, true));
}

__global__ __launch_bounds__(256) void lstm_fused(
    const float* __restrict__ x, const float* __restrict__ W_ih0_1,
    const float* __restrict__ W_ih_1, const float* __restrict__ W_hh_1,
    const float* __restrict__ b_ih_1, const float* __restrict__ b_hh_1,
    const float* __restrict__ W_ih_2, const float* __restrict__ W_hh_2,
    const float* __restrict__ b_ih_2, const float* __restrict__ b_hh_2,
    float* __restrict__ x1out, float* __restrict__ h2out) {
  __shared__ float xgF[256 * 64];  // 64 KB, fwd
  __shared__ float xgB[256 * 64];  // 64 KB, bwd

  const int tid = threadIdx.x;
  const int lane = tid & 63;
  const int w = tid >> 6;     // 0..3, one wave per SIMD
  const int np = blockIdx.x;  // 0..47
  const int nglob = 48 + np;  // stack-1 chain index (n<48 dead)

  // ---- layer-0 init (in_sz = 1): wave w covers t in [w*64, w*64+64) ----
  {
    const float bF = b_ih_1[lane] + b_hh_1[lane];
    const float bB = b_ih_1[64 + lane] + b_hh_1[64 + lane];
    const float wF = W_ih0_1[lane];
    const float wB = W_ih0_1[64 + lane];
    const int xvb = __float_as_int(x[(size_t)(w * 64 + lane) * 96 + nglob]);
    for (int ti = 0; ti < 64; ++ti) {
      const float xs = __int_as_float(__builtin_amdgcn_readlane(xvb, ti));
      xgF[(w * 64 + ti) * 64 + lane] = fmaf(wF, xs, bF);
      xgB[(w * 64 + ti) * 64 + lane] = fmaf(wB, xs, bB);
    }
  }

  // ---- rec constants (valid on all lanes; used by waves 0/1) ----
  const int g = lane & 3;
  const int r = g * 16 + (lane >> 2);
  const float s_ = (g == 2) ? 2.885390082f : -1.442695041f;
  const float m_ = (g == 2) ? -2.0f : 1.0f;
  const float b_ = (g == 2) ? 1.0f : 0.0f;
  __syncthreads();

  for (int L = 0; L < 48; ++L) {
    const bool wo = (L == 23) || (L == 47);

    // ---- rec waves (0=fwd, 1=bwd): whh slice + stride-merged base ----
    float whh[16];
    float hs[16];
    float c = 0.f;
    float* rbase = nullptr;
    int st = 0;
    if (w <= 1) {
      const float* Wl = ((L < 24) ? (W_hh_1 + (size_t)L * 2048)
                                  : (W_hh_2 + (size_t)(L - 24) * 2048)) +
                        (size_t)w * 1024 + (size_t)r * 16;
#pragma unroll
      for (int k = 0; k < 16; ++k) whh[k] = Wl[k];
#pragma unroll
      for (int k = 0; k < 16; ++k) hs[k] = 0.f;
      rbase = (w == 0) ? &xgF[r] : &xgB[255 * 64 + r];
      st = (w == 0) ? 64 : -64;
    }

    // ---- phase-A weights for layer L+1 (waves 2,3) ----
    float wf[32], wb[32], bf = 0.f, bb = 0.f;
    if (w >= 2) {
      const int M = (L < 47) ? (L + 1) : 47;  // clamp (last unused)
      const float* WihP;
      const float* bihP;
      const float* bhhP;
      if (M < 24) {
        WihP = W_ih_1 + (size_t)(M - 1) * 4096;
        bihP = b_ih_1 + (size_t)M * 128;
        bhhP = b_hh_1 + (size_t)M * 128;
      } else {
        WihP = W_ih_2 + (size_t)(M - 24) * 4096;
        bihP = b_ih_2 + (size_t)(M - 24) * 128;
        bhhP = b_hh_2 + (size_t)(M - 24) * 128;
      }
      bf = bihP[lane] + bhhP[lane];
      bb = bihP[64 + lane] + bhhP[64 + lane];
      const float4* pf =
          reinterpret_cast<const float4*>(WihP + (size_t)lane * 32);
      const float4* pb =
          reinterpret_cast<const float4*>(WihP + 2048 + (size_t)lane * 32);
#pragma unroll
      for (int q = 0; q < 8; ++q) {
        const float4 a = pf[q];
        wf[4 * q + 0] = a.x;
        wf[4 * q + 1] = a.y;
        wf[4 * q + 2] = a.z;
        wf[4 * q + 3] = a.w;
        const float4 b = pb[q];
        wb[4 * q + 0] = b.x;
        wb[4 * q + 1] = b.y;
        wb[4 * q + 2] = b.z;
        wb[4 * q + 3] = b.w;
      }
    }

    // ---- one register-only LSTM step (identical numerics) ----
    auto rec_step = [&](float gx) -> float {
      float a0 = gx, a1 = 0.f, a2 = 0.f, a3 = 0.f;
#pragma unroll
      for (int k = 0; k < 16; k += 4) {
        a0 = fmaf(whh[k + 0], hs[k + 0], a0);
        a1 = fmaf(whh[k + 1], hs[k + 1], a1);
        a2 = fmaf(whh[k + 2], hs[k + 2], a2);
        a3 = fmaf(whh[k + 3], hs[k + 3], a3);
      }
      const float gv = (a0 + a1) + (a2 + a3);
      const float e = __builtin_amdgcn_exp2f(s_ * gv);
      const float v = fmaf(m_, __builtin_amdgcn_rcpf(1.0f + e), b_);
      const float si = quad_bcast<0>(v);
      const float sf = quad_bcast<1>(v);
      const float tg = quad_bcast<2>(v);
      const float so = quad_bcast<3>(v);
      c = fmaf(sf, c, si * tg);
      const float e2 = __builtin_amdgcn_exp2f(2.885390082f * c);
      const float th = fmaf(-2.0f, __builtin_amdgcn_rcpf(1.0f + e2), 1.0f);
      const float h = so * th;
      const int hb = __float_as_int(h);
#pragma unroll
      for (int k = 0; k < 16; ++k)
        hs[k] = __int_as_float(__builtin_amdgcn_readlane(hb, 4 * k));
      return h;
    };

    // 32-step segment s: batch gate preload (32 ds_read_b32) ->
    // register-only steps -> fire-and-forget h writes (g==0 lanes land
    // h[j] at row positions [0..15]).
    auto rec_seg = [&](int s) {
      float* p = rbase + (s * 32) * st;
      float gx[32];
#pragma unroll
      for (int i = 0; i < 32; ++i) gx[i] = p[i * st];
#pragma unroll
      for (int i = 0; i < 32; ++i) p[i * st] = rec_step(gx[i]);
    };

    // ---- phase-A helpers (waves 2,3) ----
    auto compute_row = [&](int t, const float4 (&F)[4], const float4 (&Bv)[4]) {
      float f0 = bf, f1 = 0.f, f2 = 0.f, f3 = 0.f;
      float g0 = bb, g1 = 0.f, g2 = 0.f, g3 = 0.f;
#pragma unroll
      for (int q = 0; q < 4; ++q) {
        const float4 a = F[q];
        f0 = fmaf(wf[4 * q + 0], a.x, f0);
        f1 = fmaf(wf[4 * q + 1], a.y, f1);
        f2 = fmaf(wf[4 * q + 2], a.z, f2);
        f3 = fmaf(wf[4 * q + 3], a.w, f3);
        g0 = fmaf(wb[4 * q + 0], a.x, g0);
        g1 = fmaf(wb[4 * q + 1], a.y, g1);
        g2 = fmaf(wb[4 * q + 2], a.z, g2);
        g3 = fmaf(wb[4 * q + 3], a.w, g3);
        const float4 b = Bv[q];
        f0 = fmaf(wf[16 + 4 * q + 0], b.x, f0);
        f1 = fmaf(wf[16 + 4 * q + 1], b.y, f1);
        f2 = fmaf(wf[16 + 4 * q + 2], b.z, f2);
        f3 = fmaf(wf[16 + 4 * q + 3], b.w, f3);
        g0 = fmaf(wb[16 + 4 * q + 0], b.x, g0);
        g1 = fmaf(wb[16 + 4 * q + 1], b.y, g1);
        g2 = fmaf(wb[16 + 4 * q + 2], b.z, g2);
        g3 = fmaf(wb[16 + 4 * q + 3], b.w, g3);
      }
      xgF[t * 64 + lane] = (f0 + f1) + (f2 + f3);
      xgB[t * 64 + lane] = (g0 + g1) + (g2 + g3);
    };

    auto phaseA_rows = [&](int t0, int cnt) {  // cnt even, 2-row pipeline
      float4 af[4], ab4[4], nf[4], nb[4];
      {
        const float4* qf = reinterpret_cast<const float4*>(&xgF[t0 * 64]);
        const float4* qb = reinterpret_cast<const float4*>(&xgB[t0 * 64]);
#pragma unroll
        for (int q = 0; q < 4; ++q) {
          af[q] = qf[q];
          ab4[q] = qb[q];
        }
      }
      for (int i = 0; i < cnt; i += 2) {
        const int t = t0 + i;
        {
          const float4* qf =
              reinterpret_cast<const float4*>(&xgF[(t + 1) * 64]);
          const float4* qb =
              reinterpret_cast<const float4*>(&xgB[(t + 1) * 64]);
#pragma unroll
          for (int q = 0; q < 4; ++q) {
            nf[q] = qf[q];
            nb[q] = qb[q];
          }
        }
        compute_row(t, af, ab4);
        if (i + 2 < cnt) {
          const float4* qf =
              reinterpret_cast<const float4*>(&xgF[(t + 2) * 64]);
          const float4* qb =
              reinterpret_cast<const float4*>(&xgB[(t + 2) * 64]);
#pragma unroll
          for (int q = 0; q < 4; ++q) {
            af[q] = qf[q];
            ab4[q] = qb[q];
          }
        }
        compute_row(t + 1, nf, nb);
      }
    };

    // ---- S0: rec steps 0..191 (segments 0..5); waves 2,3 park ----
    if (w <= 1) {
      for (int s = 0; s < 6; ++s) rec_seg(s);
    }
    __syncthreads();  // B_a

    // ---- S1: rec steps 192..223 || phase-A rows 64..191 ----
    if (w <= 1) {
      rec_seg(6);
    } else if (!wo) {
      phaseA_rows((w == 2) ? 64 : 128, 64);
    }
    __syncthreads();  // B_b

    // ---- S2: rec steps 224..255 || phase-A rows 32..63 & 192..223 ----
    if (w <= 1) {
      rec_seg(7);
    } else if (!wo) {
      phaseA_rows((w == 2) ? 32 : 192, 32);
    }
    __syncthreads();  // B_c

    // ---- write-outs / tail phase-A ----
    if (wo) {
      float* dst = (L == 23) ? x1out : h2out;
#pragma unroll
      for (int p = 0; p < 8; ++p) {
        const int gi = p * 256 + tid;  // 0..2047 float4 chunks
        const int tt = gi >> 3;
        const int cc = gi & 7;  // 0-3 fwd, 4-7 bwd
        const float* src =
            (cc < 4) ? &xgF[tt * 64 + cc * 4] : &xgB[tt * 64 + (cc - 4) * 4];
        const float4 v = *reinterpret_cast<const float4*>(src);
        *reinterpret_cast<float4*>(dst + ((size_t)tt * 48 + np) * 32 +
                                   cc * 4) = v;
      }
      if (L == 47) break;
      __syncthreads();  // protect x1 reads from phase-A overwrite
      if (w >= 2) phaseA_rows((w == 2) ? 0 : 128, 128);  // full phase A
    } else {
      if (w >= 2) phaseA_rows((w == 2) ? 0 : 224, 32);  // tail rows
    }
    __syncthreads();  // B_d
  }
}

// fc1: y1[b,m] = relu( sum_k (h2[b,k] + x1[b,k]) * w1[m,k] + b1[m] )
// Both h2 and x1 are compact (256,1536).
__global__ __launch_bounds__(256) void fc1_kernel(
    const float* __restrict__ h2, const float* __restrict__ x1b,
    const float* __restrict__ w1, const float* __restrict__ b1,
    float* __restrict__ y1) {
  __shared__ float Zs[16][68];
  __shared__ float Ws[16][68];
  const int tid = threadIdx.x;
  const int m0 = blockIdx.x * 64;
  const int b0 = blockIdx.y * 64;
  const int rr = tid >> 2;
  const int c4 = (tid & 3) * 4;
  const int tx = tid & 15, ty = tid >> 4;

  float acc[4][4];
#pragma unroll
  for (int i = 0; i < 4; ++i)
#pragma unroll
    for (int jj = 0; jj < 4; ++jj) acc[i][jj] = 0.f;

  const bool wvalid = (m0 + rr) < 1000;
  const float* zr = h2 + (size_t)(b0 + rr) * 1536 + c4;
  const float* zr2 = x1b + (size_t)(b0 + rr) * 1536 + c4;
  const float* wr = w1 + (size_t)(m0 + rr) * 1536 + c4;

  float4 za = *reinterpret_cast<const float4*>(zr);
  float4 zb = *reinterpret_cast<const float4*>(zr2);
  float4 wv = wvalid ? *reinterpret_cast<const float4*>(wr)
                     : make_float4(0.f, 0.f, 0.f, 0.f);

  for (int k0 = 0; k0 < 1536; k0 += 16) {
    Zs[c4 + 0][rr] = za.x + zb.x;
    Zs[c4 + 1][rr] = za.y + zb.y;
    Zs[c4 + 2][rr] = za.z + zb.z;
    Zs[c4 + 3][rr] = za.w + zb.w;
    Ws[c4 + 0][rr] = wv.x;
    Ws[c4 + 1][rr] = wv.y;
    Ws[c4 + 2][rr] = wv.z;
    Ws[c4 + 3][rr] = wv.w;
    if (k0 + 16 < 1536) {
      za = *reinterpret_cast<const float4*>(zr + k0 + 16);
      zb = *reinterpret_cast<const float4*>(zr2 + k0 + 16);
      if (wvalid) wv = *reinterpret_cast<const float4*>(wr + k0 + 16);
    }
    __syncthreads();
#pragma unroll
    for (int kk = 0; kk < 16; ++kk) {
      const float4 av = *reinterpret_cast<const float4*>(&Zs[kk][ty * 4]);
      const float4 bv = *reinterpret_cast<const float4*>(&Ws[kk][tx * 4]);
      const float a_[4] = {av.x, av.y, av.z, av.w};
      const float b_[4] = {bv.x, bv.y, bv.z, bv.w};
#pragma unroll
      for (int i = 0; i < 4; ++i)
#pragma unroll
        for (int jj = 0; jj < 4; ++jj)
          acc[i][jj] = fmaf(a_[i], b_[jj], acc[i][jj]);
    }
    __syncthreads();
  }
#pragma unroll
  for (int i = 0; i < 4; ++i) {
    const int b = b0 + ty * 4 + i;
#pragma unroll
    for (int jj = 0; jj < 4; ++jj) {
      const int m = m0 + tx * 4 + jj;
      if (m < 1000) {
        float vo = acc[i][jj] + b1[m];
        y1[(size_t)b * 1000 + m] = vo > 0.f ? vo : 0.f;
      }
    }
  }
}

// fc2: out[b,p] = sum_m y1[b,m]*w2[p,m] + b2[p], p<48; FP32 store.
__global__ __launch_bounds__(64) void fc2_kernel(
    const float* __restrict__ y1, const float* __restrict__ w2,
    const float* __restrict__ b2, float* __restrict__ out) {
  __shared__ float ys[1000];
  const int b = blockIdx.x;
  for (int k = threadIdx.x; k < 1000; k += 64) ys[k] = y1[(size_t)b * 1000 + k];
  __syncthreads();
  const int p = threadIdx.x;
  if (p < 48) {
    float a0 = b2[p], a1 = 0.f, a2 = 0.f, a3 = 0.f;
    const float* wr = w2 + (size_t)p * 1000;
    for (int k = 0; k < 1000; k += 4) {
      const float4 wv = *reinterpret_cast<const float4*>(wr + k);
      a0 = fmaf(ys[k + 0], wv.x, a0);
      a1 = fmaf(ys[k + 1], wv.y, a1);
      a2 = fmaf(ys[k + 2], wv.z, a2);
      a3 = fmaf(ys[k + 3], wv.w, a3);
    }
    out[(size_t)b * 48 + p] = (a0 + a1) + (a2 + a3);
  }
}

extern "C" void kernel_launch(void* const* d_in, const int* in_sizes, int n_in,
                              void* d_out, int out_size, void* d_ws,
                              size_t ws_size, hipStream_t stream) {
  const float* x = (const float*)d_in[0];
  const float* W_ih0_1 = (const float*)d_in[1];
  const float* W_ih_1 = (const float*)d_in[2];
  const float* W_hh_1 = (const float*)d_in[3];
  const float* b_ih_1 = (const float*)d_in[4];
  const float* b_hh_1 = (const float*)d_in[5];
  const float* W_ih_2 = (const float*)d_in[6];
  const float* W_hh_2 = (const float*)d_in[7];
  const float* b_ih_2 = (const float*)d_in[8];
  const float* b_hh_2 = (const float*)d_in[9];
  const float* fc1_w = (const float*)d_in[10];
  const float* fc1_b = (const float*)d_in[11];
  const float* fc2_w = (const float*)d_in[12];
  const float* fc2_b = (const float*)d_in[13];

  float* ws = (float*)d_ws;
  float* x1b = ws;           // 393216 floats (256*48*32)
  float* h2b = ws + 393216;  // 393216 floats
  float* y1 = ws + 786432;   // 256000 floats

  lstm_fused<<<48, 256, 0, stream>>>(x, W_ih0_1, W_ih_1, W_hh_1, b_ih_1,
                                     b_hh_1, W_ih_2, W_hh_2, b_ih_2, b_hh_2,
                                     x1b, h2b);
  fc1_kernel<<<dim3(16, 4), 256, 0, stream>>>(h2b, x1b, fc1_w, fc1_b, y1);
  fc2_kernel<<<256, 64, 0, stream>>>(y1, fc2_w, fc2_b, (float*)d_out);
}